// Round 13
// baseline (305.447 us; speedup 1.0000x reference)
//
#include <hip/hip_runtime.h>

#define N_NODES 50000
#define NPAD 50048          // 782 * 64
#define N_EDGES 400000
#define HID 128
#define NUM_GRAPHS 64
#define SCAN_B 196          // ceil(N_NODES/256)
#define EC 1024             // k_agg LDS edge-metadata capacity (avg 512/block)

typedef __bf16 bf16;
typedef bf16 bf16x8 __attribute__((ext_vector_type(8)));
typedef float f32x4 __attribute__((ext_vector_type(4)));

__device__ inline bf16x8 cvt8(const float* p) {
    const float4 a = *(const float4*)p;
    const float4 b = *(const float4*)(p + 4);
    bf16x8 v;
    v[0] = (bf16)a.x; v[1] = (bf16)a.y; v[2] = (bf16)a.z; v[3] = (bf16)a.w;
    v[4] = (bf16)b.x; v[5] = (bf16)b.y; v[6] = (bf16)b.z; v[7] = (bf16)b.w;
    return v;
}

// coalesced 64x128 bf16 tile copy: LDS(ld=136) -> global rows n0..n0+63
__device__ __forceinline__ void tile_out(const bf16* lds, bf16* g, int n0, int tid) {
    #pragma unroll
    for (int u = 0; u < 4; ++u) {
        const int unit = u * 256 + tid;          // 0..1023
        const int row = unit >> 4;
        const int ci = (unit & 15) * 8;
        *(bf16x8*)&g[(size_t)(n0 + row) * HID + ci] =
            *(const bf16x8*)&lds[row * 136 + ci];
    }
}

// ---------------- CSR build ----------------
__global__ void k_hist(const int* __restrict__ edst, int* __restrict__ deg) {
    int e = blockIdx.x * 256 + threadIdx.x;
    if (e < N_EDGES) atomicAdd(&deg[edst[e]], 1);
}

__global__ void k_scan1(const int* __restrict__ deg, int* __restrict__ partial) {
    __shared__ int buf[256];
    int i = blockIdx.x * 256 + threadIdx.x;
    buf[threadIdx.x] = (i < N_NODES) ? deg[i] : 0;
    __syncthreads();
    for (int off = 128; off > 0; off >>= 1) {
        if (threadIdx.x < off) buf[threadIdx.x] += buf[threadIdx.x + off];
        __syncthreads();
    }
    if (threadIdx.x == 0) partial[blockIdx.x] = buf[0];
}

__global__ void k_scan2(int* __restrict__ partial, int* __restrict__ row_ptr) {
    __shared__ int buf[256];
    int v = (threadIdx.x < SCAN_B) ? partial[threadIdx.x] : 0;
    buf[threadIdx.x] = v;
    __syncthreads();
    for (int off = 1; off < 256; off <<= 1) {
        int t = (threadIdx.x >= off) ? buf[threadIdx.x - off] : 0;
        __syncthreads();
        buf[threadIdx.x] += t;
        __syncthreads();
    }
    if (threadIdx.x < SCAN_B) partial[threadIdx.x] = buf[threadIdx.x] - v;  // exclusive
    if (threadIdx.x == 255) row_ptr[N_NODES] = buf[255];
}

__global__ void k_scan3(const int* __restrict__ deg, const int* __restrict__ partial,
                        int* __restrict__ row_ptr, int* __restrict__ cursor) {
    __shared__ int buf[256];
    int i = blockIdx.x * 256 + threadIdx.x;
    int v = (i < N_NODES) ? deg[i] : 0;
    buf[threadIdx.x] = v;
    __syncthreads();
    for (int off = 1; off < 256; off <<= 1) {
        int t = (threadIdx.x >= off) ? buf[threadIdx.x - off] : 0;
        __syncthreads();
        buf[threadIdx.x] += t;
        __syncthreads();
    }
    if (i < N_NODES) {
        int ex = partial[blockIdx.x] + buf[threadIdx.x] - v;
        row_ptr[i] = ex;
        cursor[i] = ex;
    }
}

__global__ void k_scatter(const int* __restrict__ esrc, const int* __restrict__ edst,
                          const float* __restrict__ attr, int* __restrict__ cursor,
                          int* __restrict__ s_src, float* __restrict__ s_attr) {
    int e = blockIdx.x * 256 + threadIdx.x;
    if (e >= N_EDGES) return;
    int p = atomicAdd(&cursor[edst[e]], 1);
    s_src[p] = esrc[e];
    s_attr[p] = attr[e];
}

// ---------------- weight prep (all layers upfront): bf16 [n][k] transposes ----------------
__global__ void k_wprep(const float* __restrict__ msg_w1, const float* __restrict__ upd_w1,
                        const float* __restrict__ upd_w2,
                        bf16* __restrict__ W1t, bf16* __restrict__ U1t,
                        bf16* __restrict__ U2t) {
    const int l = blockIdx.y;
    const int n = blockIdx.x, k = threadIdx.x;
    const float* w1  = msg_w1 + (size_t)l * 257 * HID;
    const float* uw1 = upd_w1 + (size_t)l * 2 * HID * HID;
    const float* uw2 = upd_w2 + (size_t)l * HID * HID;
    if (n < 256) {
        W1t[(size_t)l * 256 * HID + n * HID + k] =
            (bf16)w1[(size_t)((n & 128) + k) * HID + (n & 127)];
    } else if (n < 384) {
        const int nn = n - 256;
        U1t[(size_t)l * HID * HID + nn * HID + k] = (bf16)uw1[(size_t)k * HID + nn];
    } else {
        const int nn = n - 384;
        U2t[(size_t)l * HID * HID + nn * HID + k] = (bf16)uw2[(size_t)k * HID + nn];
    }
}

// ---------------- W2Ut[l][j][k] = (w2 @ uw1_bot)[k][j]; b2u[l] = b2 @ uw1_bot ----------------
__global__ void k_small(const float* __restrict__ msg_w2, const float* __restrict__ upd_w1,
                        const float* __restrict__ msg_b2,
                        bf16* __restrict__ W2Ut, float* __restrict__ b2u) {
    __shared__ float row[HID];
    const int l = blockIdx.y;
    const int k = blockIdx.x, j = threadIdx.x;
    const float* w2  = msg_w2 + (size_t)l * HID * HID;
    const float* uw1 = upd_w1 + (size_t)l * 2 * HID * HID;
    const float* b2  = msg_b2 + (size_t)l * HID;
    const float* src = (k < HID) ? &w2[(size_t)k * HID] : b2;
    row[j] = src[j];
    __syncthreads();
    float acc = 0.f;
    #pragma unroll 8
    for (int m = 0; m < HID; ++m)
        acc = fmaf(row[m], uw1[(size_t)(HID + m) * HID + j], acc);
    if (k < HID) W2Ut[(size_t)l * HID * HID + (size_t)j * HID + k] = (bf16)acc;
    else b2u[l * HID + j] = acc;
}

// ---------------- fused embed + layer-0 pre (coalesced tile outputs) ----------------
__launch_bounds__(256, 4)
__global__ void k_embed_pre(const int* __restrict__ z, const float* __restrict__ embed,
                            const bf16* __restrict__ W1t, const float* __restrict__ b1,
                            bf16* __restrict__ h16, bf16* __restrict__ P, bf16* __restrict__ Q) {
    __shared__ bf16 sH[64 * 136];
    __shared__ bf16 sH2[64 * 136];
    const int tid = threadIdx.x;
    const int n0 = blockIdx.x * 64;
    {
        const int r = tid & 63, cg = tid >> 6;
        const int n = n0 + r;
        const bool valid = n < N_NODES;
        const float* src = valid ? &embed[(size_t)z[n] * HID + cg * 32] : embed;
        #pragma unroll
        for (int i = 0; i < 4; ++i) {
            bf16x8 v;
            if (valid) {
                v = cvt8(src + i * 8);
            } else {
                for (int j = 0; j < 8; ++j) v[j] = (bf16)0.f;
            }
            *(bf16x8*)&sH[r * 136 + cg * 32 + i * 8] = v;
        }
    }
    __syncthreads();
    tile_out(sH, h16, n0, tid);   // coalesced h16 write

    const int lane = tid & 63, wave = tid >> 6;
    const int lr = lane & 15, kq = (lane >> 4) * 8, rq = (lane >> 4) * 4;
    const int bcol = wave * 64;

    const f32x4 z4 = {0.f, 0.f, 0.f, 0.f};
    f32x4 acc[4][4];
    #pragma unroll
    for (int mi = 0; mi < 4; ++mi)
        #pragma unroll
        for (int ni = 0; ni < 4; ++ni) acc[mi][ni] = z4;

    #pragma unroll
    for (int ks = 0; ks < 4; ++ks) {
        bf16x8 av[4], bv[4];
        #pragma unroll
        for (int mi = 0; mi < 4; ++mi)
            av[mi] = *(const bf16x8*)&sH[(mi * 16 + lr) * 136 + ks * 32 + kq];
        #pragma unroll
        for (int ni = 0; ni < 4; ++ni)
            bv[ni] = *(const bf16x8*)&W1t[(size_t)(bcol + ni * 16 + lr) * HID + ks * 32 + kq];
        #pragma unroll
        for (int mi = 0; mi < 4; ++mi)
            #pragma unroll
            for (int ni = 0; ni < 4; ++ni)
                acc[mi][ni] = __builtin_amdgcn_mfma_f32_16x16x32_bf16(av[mi], bv[ni],
                                                                      acc[mi][ni], 0, 0, 0);
    }
    __syncthreads();   // all sH reads done; h16 copy done

    // stage: waves 0,1 -> P tile into sH; waves 2,3 -> Q tile into sH2
    {
        bf16* sOut = (bcol < 128) ? sH : sH2;
        const int cb = bcol & 127;
        #pragma unroll
        for (int ni = 0; ni < 4; ++ni) {
            const int c = cb + ni * 16 + lr;
            const float bias = (bcol >= 128) ? b1[c] : 0.f;
            #pragma unroll
            for (int mi = 0; mi < 4; ++mi)
                #pragma unroll
                for (int r = 0; r < 4; ++r)
                    sOut[(mi * 16 + rq + r) * 136 + c] = (bf16)(acc[mi][ni][r] + bias);
        }
    }
    __syncthreads();
    tile_out(sH, P, n0, tid);
    tile_out(sH2, Q, n0, tid);
}

// ---------------- standalone high-occupancy gather: aggH = segment-sum of messages -------
__launch_bounds__(256, 6)
__global__ void k_agg(const bf16* __restrict__ P, const bf16* __restrict__ Q,
                      const int* __restrict__ row_ptr, const int* __restrict__ s_src,
                      const float* __restrict__ s_attr, const float* __restrict__ w1last,
                      bf16* __restrict__ aggH) {
    __shared__ int   sEsrc[EC];
    __shared__ float sEatt[EC];
    const int tid = threadIdx.x;
    const int n0 = blockIdx.x * 64;
    const int elo = row_ptr[n0];
    const int ehi = row_ptr[min(n0 + 64, N_NODES)];
    const int ecap = min(ehi - elo, EC);
    for (int i = tid; i < ecap; i += 256) {
        sEsrc[i] = s_src[elo + i];
        sEatt[i] = s_attr[elo + i];
    }
    __syncthreads();

    const int grp = tid >> 4, ln = tid & 15, c8 = ln * 8;
    float wl[8];
    #pragma unroll
    for (int j = 0; j < 8; ++j) wl[j] = w1last[c8 + j];
    #pragma unroll
    for (int t = 0; t < 4; ++t) {
        const int n = n0 + t * 16 + grp;
        if (n >= N_NODES) continue;   // pad rows of aggH never read for valid outputs
        float a8[8];
        #pragma unroll
        for (int j = 0; j < 8; ++j) a8[j] = 0.f;
        const int lo = row_ptr[n], hi = row_ptr[n + 1];
        const bf16x8 qv = *(const bf16x8*)&Q[(size_t)n * HID + c8];
        float q8[8];
        #pragma unroll
        for (int j = 0; j < 8; ++j) q8[j] = (float)qv[j];
        const int llo = lo - elo, lhi = hi - elo;
        if (lhi <= ecap) {
            int e = llo;
            for (; e + 4 <= lhi; e += 4) {
                const int s0 = sEsrc[e], s1 = sEsrc[e + 1];
                const int s2 = sEsrc[e + 2], s3 = sEsrc[e + 3];
                const float t0 = sEatt[e], t1 = sEatt[e + 1];
                const float t2 = sEatt[e + 2], t3 = sEatt[e + 3];
                const bf16x8 p0 = *(const bf16x8*)&P[(size_t)s0 * HID + c8];
                const bf16x8 p1 = *(const bf16x8*)&P[(size_t)s1 * HID + c8];
                const bf16x8 p2 = *(const bf16x8*)&P[(size_t)s2 * HID + c8];
                const bf16x8 p3 = *(const bf16x8*)&P[(size_t)s3 * HID + c8];
                #pragma unroll
                for (int j = 0; j < 8; ++j) {
                    a8[j] += fmaxf(fmaf(t0, wl[j], q8[j] + (float)p0[j]), 0.f);
                    a8[j] += fmaxf(fmaf(t1, wl[j], q8[j] + (float)p1[j]), 0.f);
                    a8[j] += fmaxf(fmaf(t2, wl[j], q8[j] + (float)p2[j]), 0.f);
                    a8[j] += fmaxf(fmaf(t3, wl[j], q8[j] + (float)p3[j]), 0.f);
                }
            }
            for (; e < lhi; ++e) {
                const int s0 = sEsrc[e];
                const float t0 = sEatt[e];
                const bf16x8 p0 = *(const bf16x8*)&P[(size_t)s0 * HID + c8];
                #pragma unroll
                for (int j = 0; j < 8; ++j)
                    a8[j] += fmaxf(fmaf(t0, wl[j], q8[j] + (float)p0[j]), 0.f);
            }
        } else {
            for (int e = lo; e < hi; ++e) {
                const int s0 = s_src[e];
                const float t0 = s_attr[e];
                const bf16x8 p0 = *(const bf16x8*)&P[(size_t)s0 * HID + c8];
                #pragma unroll
                for (int j = 0; j < 8; ++j)
                    a8[j] += fmaxf(fmaf(t0, wl[j], q8[j] + (float)p0[j]), 0.f);
            }
        }
        bf16x8 o;
        #pragma unroll
        for (int j = 0; j < 8; ++j) o[j] = (bf16)a8[j];
        *(bf16x8*)&aggH[(size_t)n * HID + c8] = o;
    }
}

// ---------------- slim fused layer: GEMMs + residual + next-layer pre / pooling ----------
template<int DO_PRE>
__launch_bounds__(256, 4)
__global__ void k_layer(bf16* __restrict__ h16, const bf16* __restrict__ aggH,
                        const int* __restrict__ row_ptr,
                        const bf16* __restrict__ U1t, const bf16* __restrict__ W2Ut,
                        const float* __restrict__ ub1, const float* __restrict__ b2u,
                        const bf16* __restrict__ U2t, const float* __restrict__ ub2,
                        const bf16* __restrict__ W1tn, const float* __restrict__ b1n,
                        bf16* __restrict__ Pn, bf16* __restrict__ Qn,
                        const int* __restrict__ batch, float* __restrict__ pooled) {
    __shared__ bf16 sP[64 * 136];    // phase-C A tile; then Q-out stage
    __shared__ bf16 sT[64 * 136];    // relu tile; h-out/pool; P-out stage
    __shared__ float sDeg[64];
    __shared__ int sRP[65];
    const int tid = threadIdx.x;
    const int n0 = blockIdx.x * 64;

    if (tid < 65) sRP[tid] = row_ptr[min(n0 + tid, N_NODES)];
    __syncthreads();
    if (tid < 64) sDeg[tid] = (float)(sRP[tid + 1] - sRP[tid]);

    const int lane = tid & 63, wave = tid >> 6;
    const int lr = lane & 15, kq = (lane >> 4) * 8, rq = (lane >> 4) * 4;
    const int nw = wave * 32;
    const f32x4 z4 = {0.f, 0.f, 0.f, 0.f};

    // ---- Phase B: acc = h16 @ U1t^T + aggH @ W2Ut^T (A operands direct from global) ----
    f32x4 acc[4][2];
    #pragma unroll
    for (int mi = 0; mi < 4; ++mi) { acc[mi][0] = z4; acc[mi][1] = z4; }

    #pragma unroll
    for (int ks = 0; ks < 4; ++ks) {
        bf16x8 av[4], bv[2];
        #pragma unroll
        for (int mi = 0; mi < 4; ++mi)
            av[mi] = *(const bf16x8*)&h16[(size_t)(n0 + mi * 16 + lr) * HID + ks * 32 + kq];
        #pragma unroll
        for (int ni = 0; ni < 2; ++ni)
            bv[ni] = *(const bf16x8*)&U1t[(size_t)(nw + ni * 16 + lr) * HID + ks * 32 + kq];
        #pragma unroll
        for (int mi = 0; mi < 4; ++mi)
            #pragma unroll
            for (int ni = 0; ni < 2; ++ni)
                acc[mi][ni] = __builtin_amdgcn_mfma_f32_16x16x32_bf16(av[mi], bv[ni],
                                                                      acc[mi][ni], 0, 0, 0);
    }
    #pragma unroll
    for (int ks = 0; ks < 4; ++ks) {
        bf16x8 av[4], bv[2];
        #pragma unroll
        for (int mi = 0; mi < 4; ++mi)
            av[mi] = *(const bf16x8*)&aggH[(size_t)(n0 + mi * 16 + lr) * HID + ks * 32 + kq];
        #pragma unroll
        for (int ni = 0; ni < 2; ++ni)
            bv[ni] = *(const bf16x8*)&W2Ut[(size_t)(nw + ni * 16 + lr) * HID + ks * 32 + kq];
        #pragma unroll
        for (int mi = 0; mi < 4; ++mi)
            #pragma unroll
            for (int ni = 0; ni < 2; ++ni)
                acc[mi][ni] = __builtin_amdgcn_mfma_f32_16x16x32_bf16(av[mi], bv[ni],
                                                                      acc[mi][ni], 0, 0, 0);
    }
    __syncthreads();   // sDeg visible; sT free

    // bias + deg*b2u + relu -> sT
    #pragma unroll
    for (int ni = 0; ni < 2; ++ni) {
        const int c = nw + ni * 16 + lr;
        const float bb1 = ub1[c], bb2 = b2u[c];
        #pragma unroll
        for (int mi = 0; mi < 4; ++mi)
            #pragma unroll
            for (int r = 0; r < 4; ++r) {
                const int row = mi * 16 + rq + r;
                float v = acc[mi][ni][r] + bb1 + sDeg[row] * bb2;
                sT[row * 136 + c] = (bf16)fmaxf(v, 0.f);
            }
    }
    __syncthreads();   // sT ready

    // GEMM2: sT @ U2t^T
    f32x4 acc2[4][2];
    #pragma unroll
    for (int mi = 0; mi < 4; ++mi) { acc2[mi][0] = z4; acc2[mi][1] = z4; }
    #pragma unroll
    for (int ks = 0; ks < 4; ++ks) {
        bf16x8 av[4], bv[2];
        #pragma unroll
        for (int mi = 0; mi < 4; ++mi)
            av[mi] = *(const bf16x8*)&sT[(mi * 16 + lr) * 136 + ks * 32 + kq];
        #pragma unroll
        for (int ni = 0; ni < 2; ++ni)
            bv[ni] = *(const bf16x8*)&U2t[(size_t)(nw + ni * 16 + lr) * HID + ks * 32 + kq];
        #pragma unroll
        for (int mi = 0; mi < 4; ++mi)
            #pragma unroll
            for (int ni = 0; ni < 2; ++ni)
                acc2[mi][ni] = __builtin_amdgcn_mfma_f32_16x16x32_bf16(av[mi], bv[ni],
                                                                       acc2[mi][ni], 0, 0, 0);
    }
    __syncthreads();   // sT reads done

    // epilogue: nh = h_old + acc2 + ub2 -> sT (and sP for phase C)
    #pragma unroll
    for (int ni = 0; ni < 2; ++ni) {
        const int c = nw + ni * 16 + lr;
        const float bb = ub2[c];
        #pragma unroll
        for (int mi = 0; mi < 4; ++mi)
            #pragma unroll
            for (int r = 0; r < 4; ++r) {
                const int row = mi * 16 + rq + r;
                const size_t off = (size_t)(n0 + row) * HID + c;
                const float nh = (float)h16[off] + acc2[mi][ni][r] + bb;
                sT[row * 136 + c] = (bf16)nh;
                if (DO_PRE) sP[row * 136 + c] = (bf16)nh;
            }
    }
    __syncthreads();

    if (DO_PRE) {
        tile_out(sT, h16, n0, tid);   // coalesced h16 writeback

        // ---- Phase C: next-layer [P|Q] = newh @ W1tn^T (A from sP) ----
        const int bcol = wave * 64;
        f32x4 pacc[4][4];
        #pragma unroll
        for (int mi = 0; mi < 4; ++mi)
            #pragma unroll
            for (int ni = 0; ni < 4; ++ni) pacc[mi][ni] = z4;

        #pragma unroll
        for (int ks = 0; ks < 4; ++ks) {
            bf16x8 av[4], bv[4];
            #pragma unroll
            for (int mi = 0; mi < 4; ++mi)
                av[mi] = *(const bf16x8*)&sP[(mi * 16 + lr) * 136 + ks * 32 + kq];
            #pragma unroll
            for (int ni = 0; ni < 4; ++ni)
                bv[ni] = *(const bf16x8*)&W1tn[(size_t)(bcol + ni * 16 + lr) * HID + ks * 32 + kq];
            #pragma unroll
            for (int mi = 0; mi < 4; ++mi)
                #pragma unroll
                for (int ni = 0; ni < 4; ++ni)
                    pacc[mi][ni] = __builtin_amdgcn_mfma_f32_16x16x32_bf16(av[mi], bv[ni],
                                                                           pacc[mi][ni], 0, 0, 0);
        }
        __syncthreads();   // h16 copy done (sT free), sP reads done

        // stage: waves 0,1 -> P into sT; waves 2,3 -> Q into sP
        {
            bf16* sOut = (bcol < 128) ? sT : sP;
            const int cb = bcol & 127;
            #pragma unroll
            for (int ni = 0; ni < 4; ++ni) {
                const int c = cb + ni * 16 + lr;
                const float bias = (bcol >= 128) ? b1n[c] : 0.f;
                #pragma unroll
                for (int mi = 0; mi < 4; ++mi)
                    #pragma unroll
                    for (int r = 0; r < 4; ++r)
                        sOut[(mi * 16 + rq + r) * 136 + c] = (bf16)(pacc[mi][ni][r] + bias);
            }
        }
        __syncthreads();
        tile_out(sT, Pn, n0, tid);
        tile_out(sP, Qn, n0, tid);
    } else {
        // ---- fused pooling from sT (batch sorted; run-flush per graph segment) ----
        const int c = tid & 127;
        const int half = tid >> 7;
        const int rows = min(64, N_NODES - n0);
        const int rbeg = half * 32;
        const int rend = min(rbeg + 32, rows);
        int cur = -1;
        float s = 0.f;
        for (int r = rbeg; r < rend; ++r) {
            const int g = batch[n0 + r];
            const float v = (float)sT[r * 136 + c];
            if (g != cur) {
                if (cur >= 0) atomicAdd(&pooled[cur * HID + c], s);
                cur = g; s = v;
            } else {
                s += v;
            }
        }
        if (cur >= 0) atomicAdd(&pooled[cur * HID + c], s);
    }
}

// ---------------- head MLP (fp32); counts via binary search on sorted batch ----------------
__device__ inline int lb(const int* a, int n, int v) {
    int lo = 0, hi = n;
    while (lo < hi) { int m = (lo + hi) >> 1; if (a[m] < v) lo = m + 1; else hi = m; }
    return lo;
}

__global__ void k_head(const float* __restrict__ pooled, const int* __restrict__ batch,
                       const float* __restrict__ hw1, const float* __restrict__ hb1,
                       const float* __restrict__ hw2, const float* __restrict__ hb2,
                       float* __restrict__ out) {
    const int g = blockIdx.x;
    const int c = threadIdx.x;
    __shared__ float sp[HID];
    __shared__ float red[HID];
    __shared__ int sb[2];
    if (c == 0) { sb[0] = lb(batch, N_NODES, g); sb[1] = lb(batch, N_NODES, g + 1); }
    __syncthreads();
    const float cnt = fmaxf((float)(sb[1] - sb[0]), 1.f);
    sp[c] = pooled[g * HID + c] / cnt;
    __syncthreads();
    float acc = hb1[c];
    #pragma unroll 8
    for (int k = 0; k < HID; ++k) acc = fmaf(sp[k], hw1[k * HID + c], acc);
    red[c] = fmaxf(acc, 0.f) * hw2[c];
    __syncthreads();
    for (int s = 64; s > 0; s >>= 1) {
        if (c < s) red[c] += red[c + s];
        __syncthreads();
    }
    if (c == 0) out[g] = red[0] + hb2[0];
}

extern "C" void kernel_launch(void* const* d_in, const int* in_sizes, int n_in,
                              void* d_out, int out_size, void* d_ws, size_t ws_size,
                              hipStream_t stream) {
    const int*   z       = (const int*)d_in[0];
    const int*   ei      = (const int*)d_in[1];
    const float* eattr   = (const float*)d_in[2];
    const int*   batch   = (const int*)d_in[3];
    const float* embed   = (const float*)d_in[4];
    const float* msg_w1  = (const float*)d_in[5];
    const float* msg_b1  = (const float*)d_in[6];
    const float* msg_w2  = (const float*)d_in[7];
    const float* msg_b2  = (const float*)d_in[8];
    const float* upd_w1  = (const float*)d_in[9];
    const float* upd_b1  = (const float*)d_in[10];
    const float* upd_w2  = (const float*)d_in[11];
    const float* upd_b2  = (const float*)d_in[12];
    const float* head_w1 = (const float*)d_in[13];
    const float* head_b1 = (const float*)d_in[14];
    const float* head_w2 = (const float*)d_in[15];
    const float* head_b2 = (const float*)d_in[16];
    float* out = (float*)d_out;

    // workspace layout (~81 MB)
    float* pooled = (float*)d_ws;                       // 64 x 128
    float* b2u    = pooled + NUM_GRAPHS * HID;          // 3 x 128
    float* s_attr = b2u + 3 * HID;                      // E
    int* deg_i    = (int*)(s_attr + N_EDGES);
    int* row_ptr  = deg_i + N_NODES;                    // N+1
    int* partial  = row_ptr + N_NODES + 1;              // 256
    int* cursor   = partial + 256;                      // N
    int* s_src    = cursor + N_NODES;                   // E
    bf16* h16     = (bf16*)((((unsigned long long)(s_src + N_EDGES)) + 15ULL) & ~15ULL);
    bf16* aggH    = h16 + (size_t)NPAD * HID;
    bf16* P0      = aggH + (size_t)NPAD * HID;
    bf16* Q0      = P0 + (size_t)NPAD * HID;
    bf16* P1      = Q0 + (size_t)NPAD * HID;
    bf16* Q1      = P1 + (size_t)NPAD * HID;
    bf16* W1t     = Q1 + (size_t)NPAD * HID;            // 3 x 256 x 128
    bf16* U1t     = W1t + 3 * 256 * HID;                // 3 x 128 x 128
    bf16* W2Ut    = U1t + 3 * HID * HID;
    bf16* U2t     = W2Ut + 3 * HID * HID;

    const int* esrc = ei;
    const int* edst = ei + N_EDGES;

    // CSR build + all-layer weight prep
    hipMemsetAsync(deg_i, 0, N_NODES * sizeof(int), stream);
    hipMemsetAsync(pooled, 0, NUM_GRAPHS * HID * sizeof(float), stream);
    k_hist<<<(N_EDGES + 255) / 256, 256, 0, stream>>>(edst, deg_i);
    k_scan1<<<SCAN_B, 256, 0, stream>>>(deg_i, partial);
    k_scan2<<<1, 256, 0, stream>>>(partial, row_ptr);
    k_scan3<<<SCAN_B, 256, 0, stream>>>(deg_i, partial, row_ptr, cursor);
    k_scatter<<<(N_EDGES + 255) / 256, 256, 0, stream>>>(esrc, edst, eattr, cursor, s_src, s_attr);
    {
        dim3 g1(512, 3);
        k_wprep<<<g1, 128, 0, stream>>>(msg_w1, upd_w1, upd_w2, W1t, U1t, U2t);
        dim3 g2(HID + 1, 3);
        k_small<<<g2, HID, 0, stream>>>(msg_w2, upd_w1, msg_b2, W2Ut, b2u);
    }

    const int nblk = NPAD / 64;
    // embed + layer-0 pre
    k_embed_pre<<<nblk, 256, 0, stream>>>(z, embed, W1t, msg_b1, h16, P0, Q0);

    bf16* Pa = P0; bf16* Qa = Q0; bf16* Pb = P1; bf16* Qb = Q1;
    for (int l = 0; l < 3; ++l) {
        const float* w1last = msg_w1 + (size_t)l * 257 * HID + 256 * HID;
        const bf16* U1l  = U1t  + (size_t)l * HID * HID;
        const bf16* W2Ul = W2Ut + (size_t)l * HID * HID;
        const bf16* U2l  = U2t  + (size_t)l * HID * HID;
        k_agg<<<nblk, 256, 0, stream>>>(Pa, Qa, row_ptr, s_src, s_attr, w1last, aggH);
        if (l < 2) {
            k_layer<1><<<nblk, 256, 0, stream>>>(
                h16, aggH, row_ptr,
                U1l, W2Ul, upd_b1 + (size_t)l * HID, b2u + l * HID,
                U2l, upd_b2 + (size_t)l * HID,
                W1t + (size_t)(l + 1) * 256 * HID, msg_b1 + (size_t)(l + 1) * HID, Pb, Qb,
                nullptr, nullptr);
            bf16* tp = Pa; Pa = Pb; Pb = tp;
            bf16* tq = Qa; Qa = Qb; Qb = tq;
        } else {
            k_layer<0><<<nblk, 256, 0, stream>>>(
                h16, aggH, row_ptr,
                U1l, W2Ul, upd_b1 + (size_t)l * HID, b2u + l * HID,
                U2l, upd_b2 + (size_t)l * HID,
                nullptr, nullptr, nullptr, nullptr,
                batch, pooled);
        }
    }
    k_head<<<NUM_GRAPHS, 128, 0, stream>>>(pooled, batch, head_w1, head_b1, head_w2, head_b2, out);
}

// Round 14
// 267.886 us; speedup vs baseline: 1.1402x; 1.1402x over previous
//
#include <hip/hip_runtime.h>

#define N_NODES 50000
#define NPAD 50048          // 782 * 64
#define N_EDGES 400000
#define HID 128
#define NUM_GRAPHS 64
#define SCAN_B 196          // ceil(N_NODES/256)
#define ECAP 2048           // LDS edge-metadata capacity per block (avg 512)

typedef __bf16 bf16;
typedef bf16 bf16x8 __attribute__((ext_vector_type(8)));
typedef float f32x4 __attribute__((ext_vector_type(4)));

__device__ inline bf16x8 cvt8(const float* p) {
    const float4 a = *(const float4*)p;
    const float4 b = *(const float4*)(p + 4);
    bf16x8 v;
    v[0] = (bf16)a.x; v[1] = (bf16)a.y; v[2] = (bf16)a.z; v[3] = (bf16)a.w;
    v[4] = (bf16)b.x; v[5] = (bf16)b.y; v[6] = (bf16)b.z; v[7] = (bf16)b.w;
    return v;
}

// coalesced 64x128 bf16 tile copy: LDS(ld=136) -> global rows n0..n0+63
__device__ __forceinline__ void tile_out(const bf16* lds, bf16* g, int n0, int tid) {
    #pragma unroll
    for (int u = 0; u < 4; ++u) {
        const int unit = u * 256 + tid;          // 0..1023
        const int row = unit >> 4;
        const int ci = (unit & 15) * 8;
        *(bf16x8*)&g[(size_t)(n0 + row) * HID + ci] =
            *(const bf16x8*)&lds[row * 136 + ci];
    }
}

// ---------------- CSR build ----------------
__global__ void k_hist(const int* __restrict__ edst, int* __restrict__ deg) {
    int e = blockIdx.x * 256 + threadIdx.x;
    if (e < N_EDGES) atomicAdd(&deg[edst[e]], 1);
}

__global__ void k_scan1(const int* __restrict__ deg, int* __restrict__ partial) {
    __shared__ int buf[256];
    int i = blockIdx.x * 256 + threadIdx.x;
    buf[threadIdx.x] = (i < N_NODES) ? deg[i] : 0;
    __syncthreads();
    for (int off = 128; off > 0; off >>= 1) {
        if (threadIdx.x < off) buf[threadIdx.x] += buf[threadIdx.x + off];
        __syncthreads();
    }
    if (threadIdx.x == 0) partial[blockIdx.x] = buf[0];
}

__global__ void k_scan2(int* __restrict__ partial, int* __restrict__ row_ptr) {
    __shared__ int buf[256];
    int v = (threadIdx.x < SCAN_B) ? partial[threadIdx.x] : 0;
    buf[threadIdx.x] = v;
    __syncthreads();
    for (int off = 1; off < 256; off <<= 1) {
        int t = (threadIdx.x >= off) ? buf[threadIdx.x - off] : 0;
        __syncthreads();
        buf[threadIdx.x] += t;
        __syncthreads();
    }
    if (threadIdx.x < SCAN_B) partial[threadIdx.x] = buf[threadIdx.x] - v;  // exclusive
    if (threadIdx.x == 255) row_ptr[N_NODES] = buf[255];
}

__global__ void k_scan3(const int* __restrict__ deg, const int* __restrict__ partial,
                        int* __restrict__ row_ptr, int* __restrict__ cursor) {
    __shared__ int buf[256];
    int i = blockIdx.x * 256 + threadIdx.x;
    int v = (i < N_NODES) ? deg[i] : 0;
    buf[threadIdx.x] = v;
    __syncthreads();
    for (int off = 1; off < 256; off <<= 1) {
        int t = (threadIdx.x >= off) ? buf[threadIdx.x - off] : 0;
        __syncthreads();
        buf[threadIdx.x] += t;
        __syncthreads();
    }
    if (i < N_NODES) {
        int ex = partial[blockIdx.x] + buf[threadIdx.x] - v;
        row_ptr[i] = ex;
        cursor[i] = ex;
    }
}

__global__ void k_scatter(const int* __restrict__ esrc, const int* __restrict__ edst,
                          const float* __restrict__ attr, int* __restrict__ cursor,
                          int* __restrict__ s_src, float* __restrict__ s_attr) {
    int e = blockIdx.x * 256 + threadIdx.x;
    if (e >= N_EDGES) return;
    int p = atomicAdd(&cursor[edst[e]], 1);
    s_src[p] = esrc[e];
    s_attr[p] = attr[e];
}

// ---------------- weight prep (all layers upfront): bf16 [n][k] transposes ----------------
__global__ void k_wprep(const float* __restrict__ msg_w1, const float* __restrict__ upd_w1,
                        const float* __restrict__ upd_w2,
                        bf16* __restrict__ W1t, bf16* __restrict__ U1t,
                        bf16* __restrict__ U2t) {
    const int l = blockIdx.y;
    const int n = blockIdx.x, k = threadIdx.x;
    const float* w1  = msg_w1 + (size_t)l * 257 * HID;
    const float* uw1 = upd_w1 + (size_t)l * 2 * HID * HID;
    const float* uw2 = upd_w2 + (size_t)l * HID * HID;
    if (n < 256) {
        W1t[(size_t)l * 256 * HID + n * HID + k] =
            (bf16)w1[(size_t)((n & 128) + k) * HID + (n & 127)];
    } else if (n < 384) {
        const int nn = n - 256;
        U1t[(size_t)l * HID * HID + nn * HID + k] = (bf16)uw1[(size_t)k * HID + nn];
    } else {
        const int nn = n - 384;
        U2t[(size_t)l * HID * HID + nn * HID + k] = (bf16)uw2[(size_t)k * HID + nn];
    }
}

// ---------------- W2Ut[l][j][k] = (w2 @ uw1_bot)[k][j]; b2u[l] = b2 @ uw1_bot ----------------
__global__ void k_small(const float* __restrict__ msg_w2, const float* __restrict__ upd_w1,
                        const float* __restrict__ msg_b2,
                        bf16* __restrict__ W2Ut, float* __restrict__ b2u) {
    __shared__ float row[HID];
    const int l = blockIdx.y;
    const int k = blockIdx.x, j = threadIdx.x;
    const float* w2  = msg_w2 + (size_t)l * HID * HID;
    const float* uw1 = upd_w1 + (size_t)l * 2 * HID * HID;
    const float* b2  = msg_b2 + (size_t)l * HID;
    const float* src = (k < HID) ? &w2[(size_t)k * HID] : b2;
    row[j] = src[j];
    __syncthreads();
    float acc = 0.f;
    #pragma unroll 8
    for (int m = 0; m < HID; ++m)
        acc = fmaf(row[m], uw1[(size_t)(HID + m) * HID + j], acc);
    if (k < HID) W2Ut[(size_t)l * HID * HID + (size_t)j * HID + k] = (bf16)acc;
    else b2u[l * HID + j] = acc;
}

// ---------------- fused embed + layer-0 pre (coalesced tile outputs) ----------------
__launch_bounds__(256, 4)
__global__ void k_embed_pre(const int* __restrict__ z, const float* __restrict__ embed,
                            const bf16* __restrict__ W1t, const float* __restrict__ b1,
                            bf16* __restrict__ h16, bf16* __restrict__ P, bf16* __restrict__ Q) {
    __shared__ bf16 sH[64 * 136];
    __shared__ bf16 sH2[64 * 136];
    const int tid = threadIdx.x;
    const int n0 = blockIdx.x * 64;
    {
        const int r = tid & 63, cg = tid >> 6;
        const int n = n0 + r;
        const bool valid = n < N_NODES;
        const float* src = valid ? &embed[(size_t)z[n] * HID + cg * 32] : embed;
        #pragma unroll
        for (int i = 0; i < 4; ++i) {
            bf16x8 v;
            if (valid) {
                v = cvt8(src + i * 8);
            } else {
                for (int j = 0; j < 8; ++j) v[j] = (bf16)0.f;
            }
            *(bf16x8*)&sH[r * 136 + cg * 32 + i * 8] = v;
        }
    }
    __syncthreads();
    tile_out(sH, h16, n0, tid);   // coalesced h16 write

    const int lane = tid & 63, wave = tid >> 6;
    const int lr = lane & 15, kq = (lane >> 4) * 8, rq = (lane >> 4) * 4;
    const int bcol = wave * 64;

    const f32x4 z4 = {0.f, 0.f, 0.f, 0.f};
    f32x4 acc[4][4];
    #pragma unroll
    for (int mi = 0; mi < 4; ++mi)
        #pragma unroll
        for (int ni = 0; ni < 4; ++ni) acc[mi][ni] = z4;

    #pragma unroll
    for (int ks = 0; ks < 4; ++ks) {
        bf16x8 av[4], bv[4];
        #pragma unroll
        for (int mi = 0; mi < 4; ++mi)
            av[mi] = *(const bf16x8*)&sH[(mi * 16 + lr) * 136 + ks * 32 + kq];
        #pragma unroll
        for (int ni = 0; ni < 4; ++ni)
            bv[ni] = *(const bf16x8*)&W1t[(size_t)(bcol + ni * 16 + lr) * HID + ks * 32 + kq];
        #pragma unroll
        for (int mi = 0; mi < 4; ++mi)
            #pragma unroll
            for (int ni = 0; ni < 4; ++ni)
                acc[mi][ni] = __builtin_amdgcn_mfma_f32_16x16x32_bf16(av[mi], bv[ni],
                                                                      acc[mi][ni], 0, 0, 0);
    }
    __syncthreads();   // all sH reads done; h16 copy done

    // stage: waves 0,1 -> P tile into sH; waves 2,3 -> Q tile into sH2
    {
        bf16* sOut = (bcol < 128) ? sH : sH2;
        const int cb = bcol & 127;
        #pragma unroll
        for (int ni = 0; ni < 4; ++ni) {
            const int c = cb + ni * 16 + lr;
            const float bias = (bcol >= 128) ? b1[c] : 0.f;
            #pragma unroll
            for (int mi = 0; mi < 4; ++mi)
                #pragma unroll
                for (int r = 0; r < 4; ++r)
                    sOut[(mi * 16 + rq + r) * 136 + c] = (bf16)(acc[mi][ni][r] + bias);
        }
    }
    __syncthreads();
    tile_out(sH, P, n0, tid);
    tile_out(sH2, Q, n0, tid);
}

// ---------------- fused layer (LDS edge metadata + coalesced tile outputs) ----------------
template<int DO_PRE>
__launch_bounds__(256, 4)
__global__ void k_layer(bf16* __restrict__ h16,
                        const bf16* __restrict__ P, const bf16* __restrict__ Q,
                        const int* __restrict__ row_ptr, const int* __restrict__ s_src,
                        const float* __restrict__ s_attr, const float* __restrict__ w1last,
                        const bf16* __restrict__ U1t, const bf16* __restrict__ W2Ut,
                        const float* __restrict__ ub1, const float* __restrict__ b2u,
                        const bf16* __restrict__ U2t, const float* __restrict__ ub2,
                        const bf16* __restrict__ W1tn, const float* __restrict__ b1n,
                        bf16* __restrict__ Pn, bf16* __restrict__ Qn) {
    __shared__ bf16 sAgg[64 * 136];   // agg tile; then new-h (phase C in); then Q-out stage
    __shared__ bf16 sT[64 * 136];     // edge meta (phase A); relu tile; h-out; P-out stage
    __shared__ float sDeg[64];
    const int tid = threadIdx.x;
    const int n0 = blockIdx.x * 64;

    // ---- Phase A: stage edge metadata in LDS, then gather-aggregate into sAgg ----
    {
        int*   sEsrc = (int*)sT;              // ECAP*4 B = ECAP*2 bf16
        float* sEatt = (float*)(sT + ECAP * 2);
        const int elo = row_ptr[n0];
        const int ehi = row_ptr[min(n0 + 64, N_NODES)];
        const int ecap = min(ehi - elo, ECAP);
        for (int i = tid; i < ecap; i += 256) {
            sEsrc[i] = s_src[elo + i];
            sEatt[i] = s_attr[elo + i];
        }
        __syncthreads();

        const int grp = tid >> 4, ln = tid & 15, c8 = ln * 8;
        float wl[8];
        #pragma unroll
        for (int j = 0; j < 8; ++j) wl[j] = w1last[c8 + j];
        #pragma unroll
        for (int t = 0; t < 4; ++t) {
            const int row = t * 16 + grp;
            const int n = n0 + row;
            float a8[8];
            #pragma unroll
            for (int j = 0; j < 8; ++j) a8[j] = 0.f;
            if (n < N_NODES) {
                const int lo = row_ptr[n], hi = row_ptr[n + 1];
                if (ln == 0) sDeg[row] = (float)(hi - lo);
                const bf16x8 qv = *(const bf16x8*)&Q[(size_t)n * HID + c8];
                float q8[8];
                #pragma unroll
                for (int j = 0; j < 8; ++j) q8[j] = (float)qv[j];
                const int llo = lo - elo, lhi = hi - elo;
                if (lhi <= ecap) {
                    // fast path: metadata from LDS; only P-gather hits memory
                    int e = llo;
                    for (; e + 4 <= lhi; e += 4) {
                        const int s0 = sEsrc[e], s1 = sEsrc[e + 1];
                        const int s2 = sEsrc[e + 2], s3 = sEsrc[e + 3];
                        const float t0 = sEatt[e], t1 = sEatt[e + 1];
                        const float t2 = sEatt[e + 2], t3 = sEatt[e + 3];
                        const bf16x8 p0 = *(const bf16x8*)&P[(size_t)s0 * HID + c8];
                        const bf16x8 p1 = *(const bf16x8*)&P[(size_t)s1 * HID + c8];
                        const bf16x8 p2 = *(const bf16x8*)&P[(size_t)s2 * HID + c8];
                        const bf16x8 p3 = *(const bf16x8*)&P[(size_t)s3 * HID + c8];
                        #pragma unroll
                        for (int j = 0; j < 8; ++j) {
                            a8[j] += fmaxf(fmaf(t0, wl[j], q8[j] + (float)p0[j]), 0.f);
                            a8[j] += fmaxf(fmaf(t1, wl[j], q8[j] + (float)p1[j]), 0.f);
                            a8[j] += fmaxf(fmaf(t2, wl[j], q8[j] + (float)p2[j]), 0.f);
                            a8[j] += fmaxf(fmaf(t3, wl[j], q8[j] + (float)p3[j]), 0.f);
                        }
                    }
                    for (; e < lhi; ++e) {
                        const int s0 = sEsrc[e];
                        const float t0 = sEatt[e];
                        const bf16x8 p0 = *(const bf16x8*)&P[(size_t)s0 * HID + c8];
                        #pragma unroll
                        for (int j = 0; j < 8; ++j)
                            a8[j] += fmaxf(fmaf(t0, wl[j], q8[j] + (float)p0[j]), 0.f);
                    }
                } else {
                    // fallback: metadata from global (rare)
                    for (int e = lo; e < hi; ++e) {
                        const int s0 = s_src[e];
                        const float t0 = s_attr[e];
                        const bf16x8 p0 = *(const bf16x8*)&P[(size_t)s0 * HID + c8];
                        #pragma unroll
                        for (int j = 0; j < 8; ++j)
                            a8[j] += fmaxf(fmaf(t0, wl[j], q8[j] + (float)p0[j]), 0.f);
                    }
                }
            } else if (ln == 0) {
                sDeg[row] = 0.f;
            }
            bf16x8 o;
            #pragma unroll
            for (int j = 0; j < 8; ++j) o[j] = (bf16)a8[j];
            *(bf16x8*)&sAgg[row * 136 + c8] = o;
        }
    }
    __syncthreads();

    // ---- Phase B: acc = h16 @ U1t^T + agg @ W2Ut^T ----
    const int lane = tid & 63, wave = tid >> 6;
    const int lr = lane & 15, kq = (lane >> 4) * 8, rq = (lane >> 4) * 4;
    const int nw = wave * 32;
    const f32x4 z4 = {0.f, 0.f, 0.f, 0.f};

    f32x4 acc[4][2];
    #pragma unroll
    for (int mi = 0; mi < 4; ++mi) { acc[mi][0] = z4; acc[mi][1] = z4; }

    #pragma unroll
    for (int ks = 0; ks < 4; ++ks) {
        bf16x8 av[4], bv[2];
        #pragma unroll
        for (int mi = 0; mi < 4; ++mi)
            av[mi] = *(const bf16x8*)&h16[(size_t)(n0 + mi * 16 + lr) * HID + ks * 32 + kq];
        #pragma unroll
        for (int ni = 0; ni < 2; ++ni)
            bv[ni] = *(const bf16x8*)&U1t[(size_t)(nw + ni * 16 + lr) * HID + ks * 32 + kq];
        #pragma unroll
        for (int mi = 0; mi < 4; ++mi)
            #pragma unroll
            for (int ni = 0; ni < 2; ++ni)
                acc[mi][ni] = __builtin_amdgcn_mfma_f32_16x16x32_bf16(av[mi], bv[ni],
                                                                      acc[mi][ni], 0, 0, 0);
    }
    #pragma unroll
    for (int ks = 0; ks < 4; ++ks) {
        bf16x8 av[4], bv[2];
        #pragma unroll
        for (int mi = 0; mi < 4; ++mi)
            av[mi] = *(const bf16x8*)&sAgg[(mi * 16 + lr) * 136 + ks * 32 + kq];
        #pragma unroll
        for (int ni = 0; ni < 2; ++ni)
            bv[ni] = *(const bf16x8*)&W2Ut[(size_t)(nw + ni * 16 + lr) * HID + ks * 32 + kq];
        #pragma unroll
        for (int mi = 0; mi < 4; ++mi)
            #pragma unroll
            for (int ni = 0; ni < 2; ++ni)
                acc[mi][ni] = __builtin_amdgcn_mfma_f32_16x16x32_bf16(av[mi], bv[ni],
                                                                      acc[mi][ni], 0, 0, 0);
    }
    __syncthreads();   // meta reads done (sT free for relu tile)

    // bias + deg*b2u + relu -> sT
    #pragma unroll
    for (int ni = 0; ni < 2; ++ni) {
        const int c = nw + ni * 16 + lr;
        const float bb1 = ub1[c], bb2 = b2u[c];
        #pragma unroll
        for (int mi = 0; mi < 4; ++mi)
            #pragma unroll
            for (int r = 0; r < 4; ++r) {
                const int row = mi * 16 + rq + r;
                float v = acc[mi][ni][r] + bb1 + sDeg[row] * bb2;
                sT[row * 136 + c] = (bf16)fmaxf(v, 0.f);
            }
    }
    __syncthreads();   // sT ready

    // GEMM2: sT @ U2t^T
    f32x4 acc2[4][2];
    #pragma unroll
    for (int mi = 0; mi < 4; ++mi) { acc2[mi][0] = z4; acc2[mi][1] = z4; }
    #pragma unroll
    for (int ks = 0; ks < 4; ++ks) {
        bf16x8 av[4], bv[2];
        #pragma unroll
        for (int mi = 0; mi < 4; ++mi)
            av[mi] = *(const bf16x8*)&sT[(mi * 16 + lr) * 136 + ks * 32 + kq];
        #pragma unroll
        for (int ni = 0; ni < 2; ++ni)
            bv[ni] = *(const bf16x8*)&U2t[(size_t)(nw + ni * 16 + lr) * HID + ks * 32 + kq];
        #pragma unroll
        for (int mi = 0; mi < 4; ++mi)
            #pragma unroll
            for (int ni = 0; ni < 2; ++ni)
                acc2[mi][ni] = __builtin_amdgcn_mfma_f32_16x16x32_bf16(av[mi], bv[ni],
                                                                       acc2[mi][ni], 0, 0, 0);
    }
    __syncthreads();   // sT reads done

    // epilogue: nh = h_old + acc2 + ub2 -> sT (h16-out stage) and sAgg (phase C input)
    #pragma unroll
    for (int ni = 0; ni < 2; ++ni) {
        const int c = nw + ni * 16 + lr;
        const float bb = ub2[c];
        #pragma unroll
        for (int mi = 0; mi < 4; ++mi)
            #pragma unroll
            for (int r = 0; r < 4; ++r) {
                const int row = mi * 16 + rq + r;
                const size_t off = (size_t)(n0 + row) * HID + c;
                const float nh = (float)h16[off] + acc2[mi][ni][r] + bb;
                sT[row * 136 + c] = (bf16)nh;
                if (DO_PRE) sAgg[row * 136 + c] = (bf16)nh;
            }
    }
    __syncthreads();
    tile_out(sT, h16, n0, tid);   // coalesced h16 writeback

    if (DO_PRE) {
        // ---- Phase C: next-layer [P|Q] = newh @ W1tn^T (A from sAgg) ----
        const int bcol = wave * 64;
        f32x4 pacc[4][4];
        #pragma unroll
        for (int mi = 0; mi < 4; ++mi)
            #pragma unroll
            for (int ni = 0; ni < 4; ++ni) pacc[mi][ni] = z4;

        #pragma unroll
        for (int ks = 0; ks < 4; ++ks) {
            bf16x8 av[4], bv[4];
            #pragma unroll
            for (int mi = 0; mi < 4; ++mi)
                av[mi] = *(const bf16x8*)&sAgg[(mi * 16 + lr) * 136 + ks * 32 + kq];
            #pragma unroll
            for (int ni = 0; ni < 4; ++ni)
                bv[ni] = *(const bf16x8*)&W1tn[(size_t)(bcol + ni * 16 + lr) * HID + ks * 32 + kq];
            #pragma unroll
            for (int mi = 0; mi < 4; ++mi)
                #pragma unroll
                for (int ni = 0; ni < 4; ++ni)
                    pacc[mi][ni] = __builtin_amdgcn_mfma_f32_16x16x32_bf16(av[mi], bv[ni],
                                                                           pacc[mi][ni], 0, 0, 0);
        }
        __syncthreads();   // h16 copy done (sT free), sAgg reads done

        // stage: waves 0,1 -> P into sT; waves 2,3 -> Q into sAgg
        {
            bf16* sOut = (bcol < 128) ? sT : sAgg;
            const int cb = bcol & 127;
            #pragma unroll
            for (int ni = 0; ni < 4; ++ni) {
                const int c = cb + ni * 16 + lr;
                const float bias = (bcol >= 128) ? b1n[c] : 0.f;
                #pragma unroll
                for (int mi = 0; mi < 4; ++mi)
                    #pragma unroll
                    for (int r = 0; r < 4; ++r)
                        sOut[(mi * 16 + rq + r) * 136 + c] = (bf16)(pacc[mi][ni][r] + bias);
            }
        }
        __syncthreads();
        tile_out(sT, Pn, n0, tid);
        tile_out(sAgg, Qn, n0, tid);
    }
}

// ---------------- pooling: contiguous 64-row tiles, run-flush per graph segment -------------
__global__ void k_pool(const bf16* __restrict__ h16, const int* __restrict__ batch,
                       float* __restrict__ pooled) {
    const int n0 = blockIdx.x * 64;
    const int c = threadIdx.x & 127;
    const int half = threadIdx.x >> 7;
    int cur = -1;
    float s = 0.f;
    const int rbeg = n0 + half * 32;
    const int rend = min(rbeg + 32, N_NODES);
    for (int n = rbeg; n < rend; ++n) {
        const int g = batch[n];
        const float v = (float)h16[(size_t)n * HID + c];
        if (g != cur) {
            if (cur >= 0) atomicAdd(&pooled[cur * HID + c], s);
            cur = g; s = v;
        } else {
            s += v;
        }
    }
    if (cur >= 0) atomicAdd(&pooled[cur * HID + c], s);
}

// ---------------- head MLP (fp32); counts via binary search on sorted batch ----------------
__device__ inline int lb(const int* a, int n, int v) {
    int lo = 0, hi = n;
    while (lo < hi) { int m = (lo + hi) >> 1; if (a[m] < v) lo = m + 1; else hi = m; }
    return lo;
}

__global__ void k_head(const float* __restrict__ pooled, const int* __restrict__ batch,
                       const float* __restrict__ hw1, const float* __restrict__ hb1,
                       const float* __restrict__ hw2, const float* __restrict__ hb2,
                       float* __restrict__ out) {
    const int g = blockIdx.x;
    const int c = threadIdx.x;
    __shared__ float sp[HID];
    __shared__ float red[HID];
    __shared__ int sb[2];
    if (c == 0) { sb[0] = lb(batch, N_NODES, g); sb[1] = lb(batch, N_NODES, g + 1); }
    __syncthreads();
    const float cnt = fmaxf((float)(sb[1] - sb[0]), 1.f);
    sp[c] = pooled[g * HID + c] / cnt;
    __syncthreads();
    float acc = hb1[c];
    #pragma unroll 8
    for (int k = 0; k < HID; ++k) acc = fmaf(sp[k], hw1[k * HID + c], acc);
    red[c] = fmaxf(acc, 0.f) * hw2[c];
    __syncthreads();
    for (int s = 64; s > 0; s >>= 1) {
        if (c < s) red[c] += red[c + s];
        __syncthreads();
    }
    if (c == 0) out[g] = red[0] + hb2[0];
}

extern "C" void kernel_launch(void* const* d_in, const int* in_sizes, int n_in,
                              void* d_out, int out_size, void* d_ws, size_t ws_size,
                              hipStream_t stream) {
    const int*   z       = (const int*)d_in[0];
    const int*   ei      = (const int*)d_in[1];
    const float* eattr   = (const float*)d_in[2];
    const int*   batch   = (const int*)d_in[3];
    const float* embed   = (const float*)d_in[4];
    const float* msg_w1  = (const float*)d_in[5];
    const float* msg_b1  = (const float*)d_in[6];
    const float* msg_w2  = (const float*)d_in[7];
    const float* msg_b2  = (const float*)d_in[8];
    const float* upd_w1  = (const float*)d_in[9];
    const float* upd_b1  = (const float*)d_in[10];
    const float* upd_w2  = (const float*)d_in[11];
    const float* upd_b2  = (const float*)d_in[12];
    const float* head_w1 = (const float*)d_in[13];
    const float* head_b1 = (const float*)d_in[14];
    const float* head_w2 = (const float*)d_in[15];
    const float* head_b2 = (const float*)d_in[16];
    float* out = (float*)d_out;

    // workspace layout (~68 MB)
    float* pooled = (float*)d_ws;                       // 64 x 128
    float* b2u    = pooled + NUM_GRAPHS * HID;          // 3 x 128
    float* s_attr = b2u + 3 * HID;                      // E
    int* deg_i    = (int*)(s_attr + N_EDGES);
    int* row_ptr  = deg_i + N_NODES;                    // N+1
    int* partial  = row_ptr + N_NODES + 1;              // 256
    int* cursor   = partial + 256;                      // N
    int* s_src    = cursor + N_NODES;                   // E
    bf16* h16     = (bf16*)((((unsigned long long)(s_src + N_EDGES)) + 15ULL) & ~15ULL);
    bf16* P0      = h16 + (size_t)NPAD * HID;
    bf16* Q0      = P0 + (size_t)NPAD * HID;
    bf16* P1      = Q0 + (size_t)NPAD * HID;
    bf16* Q1      = P1 + (size_t)NPAD * HID;
    bf16* W1t     = Q1 + (size_t)NPAD * HID;            // 3 x 256 x 128
    bf16* U1t     = W1t + 3 * 256 * HID;                // 3 x 128 x 128
    bf16* W2Ut    = U1t + 3 * HID * HID;
    bf16* U2t     = W2Ut + 3 * HID * HID;

    const int* esrc = ei;
    const int* edst = ei + N_EDGES;

    // CSR build + all-layer weight prep
    hipMemsetAsync(deg_i, 0, N_NODES * sizeof(int), stream);
    k_hist<<<(N_EDGES + 255) / 256, 256, 0, stream>>>(edst, deg_i);
    k_scan1<<<SCAN_B, 256, 0, stream>>>(deg_i, partial);
    k_scan2<<<1, 256, 0, stream>>>(partial, row_ptr);
    k_scan3<<<SCAN_B, 256, 0, stream>>>(deg_i, partial, row_ptr, cursor);
    k_scatter<<<(N_EDGES + 255) / 256, 256, 0, stream>>>(esrc, edst, eattr, cursor, s_src, s_attr);
    {
        dim3 g1(512, 3);
        k_wprep<<<g1, 128, 0, stream>>>(msg_w1, upd_w1, upd_w2, W1t, U1t, U2t);
        dim3 g2(HID + 1, 3);
        k_small<<<g2, HID, 0, stream>>>(msg_w2, upd_w1, msg_b2, W2Ut, b2u);
    }

    const int nblk = NPAD / 64;
    // embed + layer-0 pre
    k_embed_pre<<<nblk, 256, 0, stream>>>(z, embed, W1t, msg_b1, h16, P0, Q0);

    bf16* Pa = P0; bf16* Qa = Q0; bf16* Pb = P1; bf16* Qb = Q1;
    for (int l = 0; l < 3; ++l) {
        const float* w1last = msg_w1 + (size_t)l * 257 * HID + 256 * HID;
        const bf16* U1l  = U1t  + (size_t)l * HID * HID;
        const bf16* W2Ul = W2Ut + (size_t)l * HID * HID;
        const bf16* U2l  = U2t  + (size_t)l * HID * HID;
        if (l < 2) {
            k_layer<1><<<nblk, 256, 0, stream>>>(
                h16, Pa, Qa, row_ptr, s_src, s_attr, w1last,
                U1l, W2Ul, upd_b1 + (size_t)l * HID, b2u + l * HID,
                U2l, upd_b2 + (size_t)l * HID,
                W1t + (size_t)(l + 1) * 256 * HID, msg_b1 + (size_t)(l + 1) * HID, Pb, Qb);
            bf16* tp = Pa; Pa = Pb; Pb = tp;
            bf16* tq = Qa; Qa = Qb; Qb = tq;
        } else {
            k_layer<0><<<nblk, 256, 0, stream>>>(
                h16, Pa, Qa, row_ptr, s_src, s_attr, w1last,
                U1l, W2Ul, upd_b1 + (size_t)l * HID, b2u + l * HID,
                U2l, upd_b2 + (size_t)l * HID,
                nullptr, nullptr, nullptr, nullptr);
        }
    }
    hipMemsetAsync(pooled, 0, NUM_GRAPHS * HID * sizeof(float), stream);
    k_pool<<<nblk, 256, 0, stream>>>(h16, batch, pooled);
    k_head<<<NUM_GRAPHS, 128, 0, stream>>>(pooled, batch, head_w1, head_b1, head_w2, head_b2, out);
}